// Round 4
// baseline (586.356 us; speedup 1.0000x reference)
//
#include <hip/hip_runtime.h>

typedef unsigned short u16;
typedef _Float16 half8 __attribute__((ext_vector_type(8)));
typedef float f32x4 __attribute__((ext_vector_type(4)));
typedef u16 u16x4 __attribute__((ext_vector_type(4)));
typedef u16 u16x8 __attribute__((ext_vector_type(8)));

#define MFMAH(a, b, c) __builtin_amdgcn_mfma_f32_16x16x32_f16(a, b, c, 0, 0, 0)

// f32 -> fp16 RNE
__device__ __forceinline__ u16 f2h(float f) {
  _Float16 h = (_Float16)f;
  return __builtin_bit_cast(u16, h);
}

__device__ __forceinline__ void gload_lds16(const void* g, void* l) {
  __builtin_amdgcn_global_load_lds(
      (const __attribute__((address_space(1))) void*)g,
      (__attribute__((address_space(3))) void*)l,
      16, 0, 0);
}

// ---------------- fp32 -> fp16 conversion (vectorized) ----------------
__global__ __launch_bounds__(256) void conv_f32_f16(const float* __restrict__ in,
                                                    u16* __restrict__ out, int n8) {
  int i = blockIdx.x * 256 + threadIdx.x;
  const int stride = gridDim.x * 256;
  for (; i < n8; i += stride) {
    const float4 a = reinterpret_cast<const float4*>(in)[2 * i];
    const float4 b = reinterpret_cast<const float4*>(in)[2 * i + 1];
    u16x8 o;
    o[0] = f2h(a.x); o[1] = f2h(a.y); o[2] = f2h(a.z); o[3] = f2h(a.w);
    o[4] = f2h(b.x); o[5] = f2h(b.y); o[6] = f2h(b.z); o[7] = f2h(b.w);
    reinterpret_cast<u16x8*>(out)[i] = o;
  }
}

// ---------------- GEMM: C[m,n] = sum_k A[m,k] * Bw[n,k] + bias[n] ----------------
// A row-major [M,K] fp16, Bw row-major [N,K] fp16 (torch Linear weight), bias f32.
// MODE 0: C row-major [M,N], stored FLOAT32 (final output buffer)
// MODE 1: C as [B,H,S,D] fp16   (m = b*2048+s, n = h*64+d)
// MODE 2: C as [B,H,D,S] fp16   (V transposed; packed 4-element stores along s)
template <int MODE>
__global__ __launch_bounds__(256) void gemm_bt(const u16* __restrict__ A,
                                               const u16* __restrict__ Bw,
                                               const float* __restrict__ bias,
                                               void* __restrict__ Cv,
                                               int M, int N, int K) {
  __shared__ u16 As[128 * 32];
  __shared__ u16 Bs[128 * 32];
  const int tid = threadIdx.x;
  const int lane = tid & 63;
  const int l16 = lane & 15, lhi = lane >> 4;
  const int wid = tid >> 6;
  const int wm = wid >> 1, wn = wid & 1;
  const int bm0 = blockIdx.y * 128;
  const int bn0 = blockIdx.x * 128;

  const int c0 = tid, c1 = tid + 256;
  const u16* Ag0 = A + (size_t)(bm0 + (c0 >> 2)) * K + (c0 & 3) * 8;
  const u16* Ag1 = A + (size_t)(bm0 + (c1 >> 2)) * K + (c1 & 3) * 8;
  const u16* Bg0 = Bw + (size_t)(bn0 + (c0 >> 2)) * K + (c0 & 3) * 8;
  const u16* Bg1 = Bw + (size_t)(bn0 + (c1 >> 2)) * K + (c1 & 3) * 8;

  f32x4 acc[4][4] = {};

  for (int kt = 0; kt < K; kt += 32) {
    gload_lds16(Ag0 + kt, &As[c0 * 8]);
    gload_lds16(Ag1 + kt, &As[c1 * 8]);
    gload_lds16(Bg0 + kt, &Bs[c0 * 8]);
    gload_lds16(Bg1 + kt, &Bs[c1 * 8]);
    __syncthreads();
    half8 af[4], bf[4];
#pragma unroll
    for (int f = 0; f < 4; ++f)
      af[f] = *reinterpret_cast<const half8*>(&As[(wm * 64 + f * 16 + l16) * 32 + lhi * 8]);
#pragma unroll
    for (int f = 0; f < 4; ++f)
      bf[f] = *reinterpret_cast<const half8*>(&Bs[(wn * 64 + f * 16 + l16) * 32 + lhi * 8]);
#pragma unroll
    for (int i = 0; i < 4; ++i)
#pragma unroll
      for (int j = 0; j < 4; ++j)
        acc[i][j] = MFMAH(af[i], bf[j], acc[i][j]);
    __syncthreads();
  }

#pragma unroll
  for (int i = 0; i < 4; ++i) {
    const int m0 = bm0 + wm * 64 + i * 16 + lhi * 4;
#pragma unroll
    for (int j = 0; j < 4; ++j) {
      const int n = bn0 + wn * 64 + j * 16 + l16;
      const float bb = bias[n];
      if (MODE == 0) {
        float* Cf = (float*)Cv;
#pragma unroll
        for (int r = 0; r < 4; ++r)
          Cf[(size_t)(m0 + r) * N + n] = acc[i][j][r] + bb;
      } else if (MODE == 2) {
        u16* C = (u16*)Cv;
        u16x4 pack;
#pragma unroll
        for (int r = 0; r < 4; ++r) pack[r] = f2h(acc[i][j][r] + bb);
        const size_t idx =
            ((size_t)((m0 >> 11) * 16 + (n >> 6)) * 64 + (n & 63)) * 2048 + (m0 & 2047);
        *reinterpret_cast<u16x4*>(&C[idx]) = pack;
      } else {
        u16* C = (u16*)Cv;
#pragma unroll
        for (int r = 0; r < 4; ++r) {
          const int m = m0 + r;
          const size_t idx =
              ((size_t)((m >> 11) * 16 + (n >> 6)) * 2048 + (m & 2047)) * 64 + (n & 63);
          C[idx] = f2h(acc[i][j][r] + bb);
        }
      }
    }
  }
}

// ---------------- Flash attention (swapped-QK, register-only softmax) ----------------
// Q,K: [B,H,S,D] fp16 ; VT: [B,H,D,S] fp16 ; X out: [B,S,H*D] fp16
// grid (16, 64): x = q-tile (128 rows), y = b*16+h. 4 waves, 32 q-rows/wave.
__global__ __launch_bounds__(256) void attn_fwd(const u16* __restrict__ Q,
                                                const u16* __restrict__ Kh,
                                                const u16* __restrict__ VT,
                                                u16* __restrict__ X) {
  const int tid = threadIdx.x, lane = tid & 63, w = tid >> 6;
  const int l16 = lane & 15, lhi = lane >> 4;
  const int qt = blockIdx.x, bh = blockIdx.y;
  const int b = bh >> 4, h = bh & 15;

  const size_t qrow0 = (size_t)bh * 2048 + qt * 128 + w * 32;
  half8 qf[2][2];
#pragma unroll
  for (int fq = 0; fq < 2; ++fq)
#pragma unroll
    for (int ks = 0; ks < 2; ++ks)
      qf[fq][ks] = *reinterpret_cast<const half8*>(
          &Q[(qrow0 + fq * 16 + l16) * 64 + ks * 32 + lhi * 8]);

  f32x4 o[2][4] = {};
  float mrow[2] = {-1e30f, -1e30f};
  float srow[2] = {0.0f, 0.0f};

  const u16* Kb = Kh + (size_t)bh * 2048 * 64;
  const u16* Vb = VT + (size_t)bh * 64 * 2048;

  for (int kb = 0; kb < 2048; kb += 32) {
    // ---- scores: sc[fq][fk] = mfma(K_frag, Q_frag): rows=keys, cols=q ----
    f32x4 sc[2][2] = {};
#pragma unroll
    for (int fk = 0; fk < 2; ++fk)
#pragma unroll
      for (int ks = 0; ks < 2; ++ks) {
        half8 kf = *reinterpret_cast<const half8*>(
            &Kb[(size_t)(kb + fk * 16 + l16) * 64 + ks * 32 + lhi * 8]);
#pragma unroll
        for (int fq = 0; fq < 2; ++fq) sc[fq][fk] = MFMAH(kf, qf[fq][ks], sc[fq][fk]);
      }
    // ---- online softmax: lane owns q-row fq*16+l16, holding 8 key-values ----
    half8 pa[2];
    float sc_b[2][4];
#pragma unroll
    for (int fq = 0; fq < 2; ++fq) {
      float m8 = sc[fq][0][0];
#pragma unroll
      for (int fk = 0; fk < 2; ++fk)
#pragma unroll
        for (int r = 0; r < 4; ++r) m8 = fmaxf(m8, sc[fq][fk][r]);
      m8 = fmaxf(m8, __shfl_xor(m8, 16));
      m8 = fmaxf(m8, __shfl_xor(m8, 32));
      const float nm = fmaxf(mrow[fq], m8);
      const float scl = __expf(mrow[fq] - nm);
      mrow[fq] = nm;
      float su = 0.0f;
#pragma unroll
      for (int fk = 0; fk < 2; ++fk)
#pragma unroll
        for (int r = 0; r < 4; ++r) {
          const float p = __expf(sc[fq][fk][r] - nm);
          su += p;
          pa[fq][fk * 4 + r] = (_Float16)p;
        }
      su += __shfl_xor(su, 16);
      su += __shfl_xor(su, 32);
      srow[fq] = srow[fq] * scl + su;
#pragma unroll
      for (int r = 0; r < 4; ++r) sc_b[fq][r] = __shfl(scl, lhi * 4 + r);
    }
#pragma unroll
    for (int fq = 0; fq < 2; ++fq)
#pragma unroll
      for (int fd = 0; fd < 4; ++fd)
#pragma unroll
        for (int r = 0; r < 4; ++r) o[fq][fd][r] *= sc_b[fq][r];
    // ---- PV: O += P * V ; V slots placed to match P's slot layout ----
#pragma unroll
    for (int fd = 0; fd < 4; ++fd) {
      const u16* vr = &Vb[(size_t)(fd * 16 + l16) * 2048 + kb + lhi * 4];
      const u16x4 v0 = *reinterpret_cast<const u16x4*>(vr);
      const u16x4 v1 = *reinterpret_cast<const u16x4*>(vr + 16);
      u16x8 vv;
#pragma unroll
      for (int r = 0; r < 4; ++r) { vv[r] = v0[r]; vv[4 + r] = v1[r]; }
      const half8 vf = __builtin_bit_cast(half8, vv);
#pragma unroll
      for (int fq = 0; fq < 2; ++fq) o[fq][fd] = MFMAH(pa[fq], vf, o[fq][fd]);
    }
  }
  // ---- epilogue: X[b, q, h*64 + d] = O / srow ----
#pragma unroll
  for (int fq = 0; fq < 2; ++fq) {
    float inv[4];
#pragma unroll
    for (int r = 0; r < 4; ++r) inv[r] = 1.0f / __shfl(srow[fq], lhi * 4 + r);
#pragma unroll
    for (int r = 0; r < 4; ++r) {
      const int q = qt * 128 + w * 32 + fq * 16 + lhi * 4 + r;
#pragma unroll
      for (int fd = 0; fd < 4; ++fd) {
        const int col = h * 64 + fd * 16 + l16;
        X[((size_t)b * 2048 + q) * 1024 + col] = f2h(o[fq][fd][r] * inv[r]);
      }
    }
  }
}

__global__ void write_loss(float* out, int idx) { out[idx] = 0.0f; }

// ---------------- launch ----------------
extern "C" void kernel_launch(void* const* d_in, const int* in_sizes, int n_in,
                              void* d_out, int out_size, void* d_ws, size_t ws_size,
                              hipStream_t stream) {
  const float* q_f  = (const float*)d_in[0];
  const float* k_f  = (const float*)d_in[1];
  const float* v_f  = (const float*)d_in[2];
  const float* Wq_f = (const float*)d_in[4];
  const float* bq   = (const float*)d_in[5];
  const float* Wk_f = (const float*)d_in[6];
  const float* bk   = (const float*)d_in[7];
  const float* Wv_f = (const float*)d_in[8];
  const float* bv   = (const float*)d_in[9];
  const float* Wo_f = (const float*)d_in[10];
  const float* bo   = (const float*)d_in[11];

  const int SZ = 4 * 2048 * 1024;  // 8388608
  const int SW = 1024 * 1024;      // 1048576

  u16* ws = (u16*)d_ws;
  u16* qb   = ws;                // fp16 inputs
  u16* kbuf = qb + SZ;
  u16* vbuf = kbuf + SZ;
  u16* wqb = vbuf + SZ;          // fp16 weights
  u16* wkb = wqb + SW;
  u16* wvb = wkb + SW;
  u16* wob = wvb + SW;
  u16* Qb  = wob + SW;           // [B,H,S,D]
  u16* Kb  = Qb + SZ;            // [B,H,S,D]
  u16* VTb = Kb + SZ;            // [B,H,D,S]
  u16* Xb  = VTb + SZ;           // [B,S,H*D]
  const size_t need_bytes = (size_t)(7 * SZ + 4 * SW) * 2;
  if (ws_size < need_bytes) return;

  conv_f32_f16<<<2048, 256, 0, stream>>>(q_f, qb, SZ / 8);
  conv_f32_f16<<<2048, 256, 0, stream>>>(k_f, kbuf, SZ / 8);
  conv_f32_f16<<<2048, 256, 0, stream>>>(v_f, vbuf, SZ / 8);
  conv_f32_f16<<<512, 256, 0, stream>>>(Wq_f, wqb, SW / 8);
  conv_f32_f16<<<512, 256, 0, stream>>>(Wk_f, wkb, SW / 8);
  conv_f32_f16<<<512, 256, 0, stream>>>(Wv_f, wvb, SW / 8);
  conv_f32_f16<<<512, 256, 0, stream>>>(Wo_f, wob, SW / 8);

  dim3 gg(1024 / 128, 8192 / 128);
  gemm_bt<1><<<gg, 256, 0, stream>>>(qb, wqb, bq, Qb, 8192, 1024, 1024);
  gemm_bt<1><<<gg, 256, 0, stream>>>(kbuf, wkb, bk, Kb, 8192, 1024, 1024);
  gemm_bt<2><<<gg, 256, 0, stream>>>(vbuf, wvb, bv, VTb, 8192, 1024, 1024);

  attn_fwd<<<dim3(16, 64), 256, 0, stream>>>(Qb, Kb, VTb, Xb);

  gemm_bt<0><<<gg, 256, 0, stream>>>(Xb, wob, bo, d_out, 8192, 1024, 1024);
  write_loss<<<1, 1, 0, stream>>>((float*)d_out, out_size - 1);
}

// Round 6
// 378.764 us; speedup vs baseline: 1.5481x; 1.5481x over previous
//
#include <hip/hip_runtime.h>

typedef unsigned short u16;
typedef _Float16 half8 __attribute__((ext_vector_type(8)));
typedef _Float16 h2 __attribute__((ext_vector_type(2)));
typedef float f32x4 __attribute__((ext_vector_type(4)));
typedef u16 u16x4 __attribute__((ext_vector_type(4)));
typedef u16 u16x8 __attribute__((ext_vector_type(8)));

#define MFMAH(a, b, c) __builtin_amdgcn_mfma_f32_16x16x32_f16(a, b, c, 0, 0, 0)

constexpr float LOG2E = 1.44269504088896f;
constexpr float THR = 12.0f;  // defer-max threshold in log2 units (p <= 2^12, fp16-safe)

// f32 -> fp16 RNE
__device__ __forceinline__ u16 f2h(float f) {
  _Float16 h = (_Float16)f;
  return __builtin_bit_cast(u16, h);
}
// packed f32x2 -> fp16x2 (RTZ)
__device__ __forceinline__ h2 pkrtz(float a, float b) {
  return __builtin_bit_cast(h2, __builtin_amdgcn_cvt_pkrtz(a, b));
}

__device__ __forceinline__ void gload_lds16(const void* g, void* l) {
  __builtin_amdgcn_global_load_lds(
      (const __attribute__((address_space(1))) void*)g,
      (__attribute__((address_space(3))) void*)l,
      16, 0, 0);
}

// ---------------- fp32 -> fp16 conversion (vectorized) ----------------
__global__ __launch_bounds__(256) void conv_f32_f16(const float* __restrict__ in,
                                                    u16* __restrict__ out, int n8) {
  int i = blockIdx.x * 256 + threadIdx.x;
  const int stride = gridDim.x * 256;
  for (; i < n8; i += stride) {
    const float4 a = reinterpret_cast<const float4*>(in)[2 * i];
    const float4 b = reinterpret_cast<const float4*>(in)[2 * i + 1];
    u16x8 o;
    o[0] = f2h(a.x); o[1] = f2h(a.y); o[2] = f2h(a.z); o[3] = f2h(a.w);
    o[4] = f2h(b.x); o[5] = f2h(b.y); o[6] = f2h(b.z); o[7] = f2h(b.w);
    reinterpret_cast<u16x8*>(out)[i] = o;
  }
}

// ---------------- GEMM: C[m,n] = (sum_k A[m,k]*Bw[n,k] + bias[n]) * scale ----------------
// MODE 0: C row-major [M,N] FLOAT32 (final output buffer)
// MODE 1: C as [B,H,S,D] fp16 (m = b*2048+s, n = h*64+d); scale=log2e for Q
// MODE 2: C in PV-fragment order fp16:
//         idx = ((head*64 + s/32)*64 + d)*32 + perm(s%32), perm(j)=((j>>2)&3)*8+((j>>4)&1)*4+(j&3)
template <int MODE>
__global__ __launch_bounds__(256) void gemm_bt(const u16* __restrict__ A,
                                               const u16* __restrict__ Bw,
                                               const float* __restrict__ bias,
                                               void* __restrict__ Cv,
                                               int M, int N, int K, float scale) {
  __shared__ u16 As[128 * 32];
  __shared__ u16 Bs[128 * 32];
  const int tid = threadIdx.x;
  const int lane = tid & 63;
  const int l16 = lane & 15, lhi = lane >> 4;
  const int wid = tid >> 6;
  const int wm = wid >> 1, wn = wid & 1;
  const int bm0 = blockIdx.y * 128;
  const int bn0 = blockIdx.x * 128;

  const int c0 = tid, c1 = tid + 256;
  const u16* Ag0 = A + (size_t)(bm0 + (c0 >> 2)) * K + (c0 & 3) * 8;
  const u16* Ag1 = A + (size_t)(bm0 + (c1 >> 2)) * K + (c1 & 3) * 8;
  const u16* Bg0 = Bw + (size_t)(bn0 + (c0 >> 2)) * K + (c0 & 3) * 8;
  const u16* Bg1 = Bw + (size_t)(bn0 + (c1 >> 2)) * K + (c1 & 3) * 8;

  f32x4 acc[4][4] = {};

  for (int kt = 0; kt < K; kt += 32) {
    gload_lds16(Ag0 + kt, &As[c0 * 8]);
    gload_lds16(Ag1 + kt, &As[c1 * 8]);
    gload_lds16(Bg0 + kt, &Bs[c0 * 8]);
    gload_lds16(Bg1 + kt, &Bs[c1 * 8]);
    __syncthreads();
    half8 af[4], bf[4];
#pragma unroll
    for (int f = 0; f < 4; ++f)
      af[f] = *reinterpret_cast<const half8*>(&As[(wm * 64 + f * 16 + l16) * 32 + lhi * 8]);
#pragma unroll
    for (int f = 0; f < 4; ++f)
      bf[f] = *reinterpret_cast<const half8*>(&Bs[(wn * 64 + f * 16 + l16) * 32 + lhi * 8]);
#pragma unroll
    for (int i = 0; i < 4; ++i)
#pragma unroll
      for (int j = 0; j < 4; ++j)
        acc[i][j] = MFMAH(af[i], bf[j], acc[i][j]);
    __syncthreads();
  }

#pragma unroll
  for (int i = 0; i < 4; ++i) {
    const int m0 = bm0 + wm * 64 + i * 16 + lhi * 4;
#pragma unroll
    for (int j = 0; j < 4; ++j) {
      const int n = bn0 + wn * 64 + j * 16 + l16;
      const float bb = bias[n];
      if (MODE == 0) {
        float* Cf = (float*)Cv;
#pragma unroll
        for (int r = 0; r < 4; ++r)
          Cf[(size_t)(m0 + r) * N + n] = acc[i][j][r] + bb;
      } else if (MODE == 2) {
        u16* C = (u16*)Cv;
        u16x4 pack;
#pragma unroll
        for (int r = 0; r < 4; ++r) pack[r] = f2h(acc[i][j][r] + bb);
        const int head = (m0 >> 11) * 16 + (n >> 6);
        const int s0 = m0 & 2047;
        const int d = n & 63;
        const size_t idx = (((size_t)head * 64 + (s0 >> 5)) * 64 + d) * 32 +
                           ((s0 >> 2) & 3) * 8 + ((s0 >> 4) & 1) * 4;
        *reinterpret_cast<u16x4*>(&C[idx]) = pack;
      } else {
        u16* C = (u16*)Cv;
#pragma unroll
        for (int r = 0; r < 4; ++r) {
          const int m = m0 + r;
          const size_t idx =
              ((size_t)((m >> 11) * 16 + (n >> 6)) * 2048 + (m & 2047)) * 64 + (n & 63);
          C[idx] = f2h((acc[i][j][r] + bb) * scale);
        }
      }
    }
  }
}

// ---------------- Flash attention: KVBLK=64, defer-max, no in-loop cross-lane ----------------
// Q,K: [B,H,S,D] fp16 (Q pre-scaled by log2e); VL: fragment-order V; X: [B,S,H*D] fp16
__device__ __forceinline__ void attn_tile(int kb, const u16* __restrict__ Kb,
                                          const u16* __restrict__ VLh,
                                          const half8 (&qf)[2][2], half8 (&kfc)[4][2],
                                          half8 (&kfn)[4][2], f32x4 (&o)[2][4],
                                          float (&mrow)[2], float (&ssum)[2], int l16,
                                          int lhi) {
  // V fragments for this tile: one coalesced 16B load each
  u16x8 vraw[4][2];
#pragma unroll
  for (int fd = 0; fd < 4; ++fd)
#pragma unroll
    for (int t = 0; t < 2; ++t)
      vraw[fd][t] = *reinterpret_cast<const u16x8*>(
          &VLh[(((size_t)(kb >> 5) + t) * 64 + fd * 16 + l16) * 32 + lhi * 8]);
  // K prefetch for next tile (wrapped; redundant on last iter, harmless)
  const int kn = (kb + 64) & 2047;
#pragma unroll
  for (int fk = 0; fk < 4; ++fk)
#pragma unroll
    for (int ks = 0; ks < 2; ++ks)
      kfn[fk][ks] = *reinterpret_cast<const half8*>(
          &Kb[(size_t)(kn + fk * 16 + l16) * 64 + ks * 32 + lhi * 8]);
  // QK^T (scores in log2 units; rows=keys, cols=q)
  f32x4 sc[2][4] = {};
#pragma unroll
  for (int fk = 0; fk < 4; ++fk)
#pragma unroll
    for (int ks = 0; ks < 2; ++ks)
#pragma unroll
      for (int fq = 0; fq < 2; ++fq)
        sc[fq][fk] = MFMAH(kfc[fk][ks], qf[fq][ks], sc[fq][fk]);
  // per-lane local max; rescale only if any row grew past THR
  float lm[2];
#pragma unroll
  for (int fq = 0; fq < 2; ++fq) {
    float v = sc[fq][0][0];
#pragma unroll
    for (int fk = 0; fk < 4; ++fk)
#pragma unroll
      for (int r = 0; r < 4; ++r) v = fmaxf(v, sc[fq][fk][r]);
    lm[fq] = v;
  }
  const int trig = (lm[0] > mrow[0] + THR) || (lm[1] > mrow[1] + THR);
  if (__any(trig)) {
#pragma unroll
    for (int fq = 0; fq < 2; ++fq) {
      float rm = lm[fq];
      rm = fmaxf(rm, __shfl_xor(rm, 16));
      rm = fmaxf(rm, __shfl_xor(rm, 32));
      const float nm = fmaxf(mrow[fq], rm);
      const float scl = __builtin_amdgcn_exp2f(mrow[fq] - nm);
      mrow[fq] = nm;
      ssum[fq] *= scl;
      float sb[4];
#pragma unroll
      for (int r = 0; r < 4; ++r) sb[r] = __shfl(scl, lhi * 4 + r);
#pragma unroll
      for (int fd = 0; fd < 4; ++fd)
#pragma unroll
        for (int r = 0; r < 4; ++r) o[fq][fd][r] *= sb[r];
    }
  }
  // exp2 + pack P to fp16 + PV
#pragma unroll
  for (int fq = 0; fq < 2; ++fq) {
    union { half8 v; h2 h[4]; } pa[2];
#pragma unroll
    for (int fk = 0; fk < 4; ++fk) {
      const float p0 = __builtin_amdgcn_exp2f(sc[fq][fk][0] - mrow[fq]);
      const float p1 = __builtin_amdgcn_exp2f(sc[fq][fk][1] - mrow[fq]);
      const float p2 = __builtin_amdgcn_exp2f(sc[fq][fk][2] - mrow[fq]);
      const float p3 = __builtin_amdgcn_exp2f(sc[fq][fk][3] - mrow[fq]);
      ssum[fq] += (p0 + p1) + (p2 + p3);
      pa[fk >> 1].h[(fk & 1) * 2 + 0] = pkrtz(p0, p1);
      pa[fk >> 1].h[(fk & 1) * 2 + 1] = pkrtz(p2, p3);
    }
#pragma unroll
    for (int fd = 0; fd < 4; ++fd)
#pragma unroll
      for (int t = 0; t < 2; ++t)
        o[fq][fd] = MFMAH(pa[t].v, __builtin_bit_cast(half8, vraw[fd][t]), o[fq][fd]);
  }
}

__global__ __launch_bounds__(256, 2) void attn_fwd(const u16* __restrict__ Q,
                                                   const u16* __restrict__ Kh,
                                                   const u16* __restrict__ VL,
                                                   u16* __restrict__ X) {
  const int tid = threadIdx.x, lane = tid & 63, w = tid >> 6;
  const int l16 = lane & 15, lhi = lane >> 4;
  const int qt = blockIdx.x, bh = blockIdx.y;
  const int b = bh >> 4, h = bh & 15;

  const size_t qrow0 = (size_t)bh * 2048 + qt * 128 + w * 32;
  half8 qf[2][2];
#pragma unroll
  for (int fq = 0; fq < 2; ++fq)
#pragma unroll
    for (int ks = 0; ks < 2; ++ks)
      qf[fq][ks] = *reinterpret_cast<const half8*>(
          &Q[(qrow0 + fq * 16 + l16) * 64 + ks * 32 + lhi * 8]);

  f32x4 o[2][4] = {};
  float mrow[2] = {-1e30f, -1e30f};
  float ssum[2] = {0.0f, 0.0f};

  const u16* Kb = Kh + (size_t)bh * 2048 * 64;
  const u16* VLh = VL + (size_t)bh * 64 * 64 * 32;

  half8 kfA[4][2], kfB[4][2];
#pragma unroll
  for (int fk = 0; fk < 4; ++fk)
#pragma unroll
    for (int ks = 0; ks < 2; ++ks)
      kfA[fk][ks] = *reinterpret_cast<const half8*>(
          &Kb[(size_t)(fk * 16 + l16) * 64 + ks * 32 + lhi * 8]);

  for (int kb = 0; kb < 2048; kb += 128) {
    attn_tile(kb, Kb, VLh, qf, kfA, kfB, o, mrow, ssum, l16, lhi);
    attn_tile(kb + 64, Kb, VLh, qf, kfB, kfA, o, mrow, ssum, l16, lhi);
  }

  // epilogue: reduce ssum across the 4 lanes of each row, normalize, store
#pragma unroll
  for (int fq = 0; fq < 2; ++fq) {
    float ss = ssum[fq];
    ss += __shfl_xor(ss, 16);
    ss += __shfl_xor(ss, 32);
    float iv[4];
#pragma unroll
    for (int r = 0; r < 4; ++r) iv[r] = 1.0f / __shfl(ss, lhi * 4 + r);
#pragma unroll
    for (int r = 0; r < 4; ++r) {
      const int q = qt * 128 + w * 32 + fq * 16 + lhi * 4 + r;
#pragma unroll
      for (int fd = 0; fd < 4; ++fd) {
        const int col = h * 64 + fd * 16 + l16;
        X[((size_t)b * 2048 + q) * 1024 + col] = f2h(o[fq][fd][r] * iv[r]);
      }
    }
  }
}

__global__ void write_loss(float* out, int idx) { out[idx] = 0.0f; }

// ---------------- launch ----------------
extern "C" void kernel_launch(void* const* d_in, const int* in_sizes, int n_in,
                              void* d_out, int out_size, void* d_ws, size_t ws_size,
                              hipStream_t stream) {
  const float* q_f  = (const float*)d_in[0];
  const float* k_f  = (const float*)d_in[1];
  const float* v_f  = (const float*)d_in[2];
  const float* Wq_f = (const float*)d_in[4];
  const float* bq   = (const float*)d_in[5];
  const float* Wk_f = (const float*)d_in[6];
  const float* bk   = (const float*)d_in[7];
  const float* Wv_f = (const float*)d_in[8];
  const float* bv   = (const float*)d_in[9];
  const float* Wo_f = (const float*)d_in[10];
  const float* bo   = (const float*)d_in[11];

  const int SZ = 4 * 2048 * 1024;  // 8388608
  const int SW = 1024 * 1024;      // 1048576

  u16* ws = (u16*)d_ws;
  u16* qb   = ws;                // fp16 inputs
  u16* kbuf = qb + SZ;
  u16* vbuf = kbuf + SZ;
  u16* wqb = vbuf + SZ;          // fp16 weights
  u16* wkb = wqb + SW;
  u16* wvb = wkb + SW;
  u16* wob = wvb + SW;
  u16* Qb  = wob + SW;           // [B,H,S,D], pre-scaled by log2e
  u16* Kb  = Qb + SZ;            // [B,H,S,D]
  u16* VLb = Kb + SZ;            // fragment-order V
  u16* Xb  = VLb + SZ;           // [B,S,H*D]
  const size_t need_bytes = (size_t)(7 * SZ + 4 * SW) * 2;
  if (ws_size < need_bytes) return;

  conv_f32_f16<<<2048, 256, 0, stream>>>(q_f, qb, SZ / 8);
  conv_f32_f16<<<2048, 256, 0, stream>>>(k_f, kbuf, SZ / 8);
  conv_f32_f16<<<2048, 256, 0, stream>>>(v_f, vbuf, SZ / 8);
  conv_f32_f16<<<512, 256, 0, stream>>>(Wq_f, wqb, SW / 8);
  conv_f32_f16<<<512, 256, 0, stream>>>(Wk_f, wkb, SW / 8);
  conv_f32_f16<<<512, 256, 0, stream>>>(Wv_f, wvb, SW / 8);
  conv_f32_f16<<<512, 256, 0, stream>>>(Wo_f, wob, SW / 8);

  dim3 gg(1024 / 128, 8192 / 128);
  gemm_bt<1><<<gg, 256, 0, stream>>>(qb, wqb, bq, Qb, 8192, 1024, 1024, LOG2E);
  gemm_bt<1><<<gg, 256, 0, stream>>>(kbuf, wkb, bk, Kb, 8192, 1024, 1024, 1.0f);
  gemm_bt<2><<<gg, 256, 0, stream>>>(vbuf, wvb, bv, VLb, 8192, 1024, 1024, 1.0f);

  attn_fwd<<<dim3(16, 64), 256, 0, stream>>>(Qb, Kb, VLb, Xb);

  gemm_bt<0><<<gg, 256, 0, stream>>>(Xb, wob, bo, d_out, 8192, 1024, 1024, 1.0f);
  write_loss<<<1, 1, 0, stream>>>((float*)d_out, out_size - 1);
}

// Round 7
// 252.394 us; speedup vs baseline: 2.3232x; 1.5007x over previous
//
#include <hip/hip_runtime.h>

typedef unsigned short u16;
typedef _Float16 half8 __attribute__((ext_vector_type(8)));
typedef _Float16 h2 __attribute__((ext_vector_type(2)));
typedef float f32x4 __attribute__((ext_vector_type(4)));
typedef u16 u16x4 __attribute__((ext_vector_type(4)));
typedef u16 u16x8 __attribute__((ext_vector_type(8)));

#define MFMAH(a, b, c) __builtin_amdgcn_mfma_f32_16x16x32_f16(a, b, c, 0, 0, 0)

constexpr float LOG2E = 1.44269504088896f;
constexpr float THR = 12.0f;  // defer-max threshold in log2 units (p <= 2^12, fp16-safe)

// f32 -> fp16 RNE
__device__ __forceinline__ u16 f2h(float f) {
  _Float16 h = (_Float16)f;
  return __builtin_bit_cast(u16, h);
}
// packed f32x2 -> fp16x2 (RTZ)
__device__ __forceinline__ h2 pkrtz(float a, float b) {
  return __builtin_bit_cast(h2, __builtin_amdgcn_cvt_pkrtz(a, b));
}

__device__ __forceinline__ void gload_lds16(const void* g, void* l) {
  __builtin_amdgcn_global_load_lds(
      (const __attribute__((address_space(1))) void*)g,
      (__attribute__((address_space(3))) void*)l,
      16, 0, 0);
}

// ---------------- fp32 -> fp16 conversion (vectorized) ----------------
__global__ __launch_bounds__(256) void conv_f32_f16(const float* __restrict__ in,
                                                    u16* __restrict__ out, int n8) {
  int i = blockIdx.x * 256 + threadIdx.x;
  const int stride = gridDim.x * 256;
  for (; i < n8; i += stride) {
    const float4 a = reinterpret_cast<const float4*>(in)[2 * i];
    const float4 b = reinterpret_cast<const float4*>(in)[2 * i + 1];
    u16x8 o;
    o[0] = f2h(a.x); o[1] = f2h(a.y); o[2] = f2h(a.z); o[3] = f2h(a.w);
    o[4] = f2h(b.x); o[5] = f2h(b.y); o[6] = f2h(b.z); o[7] = f2h(b.w);
    reinterpret_cast<u16x8*>(out)[i] = o;
  }
}

// ---------------- GEMM: C[m,n] = (sum_k A[m,k]*Bw[n,k] + bias[n]) * scale ----------------
// MODE 0: C row-major [M,N] FLOAT32 (final output buffer)
// MODE 1: C as [B,H,S,D] fp16 (m = b*2048+s, n = h*64+d); scale=log2e for Q
// MODE 2: C in PV-fragment order fp16:
//         idx = ((head*64 + s/32)*64 + d)*32 + perm(s%32), perm(j)=((j>>2)&3)*8+((j>>4)&1)*4+(j&3)
template <int MODE>
__global__ __launch_bounds__(256) void gemm_bt(const u16* __restrict__ A,
                                               const u16* __restrict__ Bw,
                                               const float* __restrict__ bias,
                                               void* __restrict__ Cv,
                                               int M, int N, int K, float scale) {
  __shared__ u16 As[128 * 32];
  __shared__ u16 Bs[128 * 32];
  const int tid = threadIdx.x;
  const int lane = tid & 63;
  const int l16 = lane & 15, lhi = lane >> 4;
  const int wid = tid >> 6;
  const int wm = wid >> 1, wn = wid & 1;
  const int bm0 = blockIdx.y * 128;
  const int bn0 = blockIdx.x * 128;

  const int c0 = tid, c1 = tid + 256;
  const u16* Ag0 = A + (size_t)(bm0 + (c0 >> 2)) * K + (c0 & 3) * 8;
  const u16* Ag1 = A + (size_t)(bm0 + (c1 >> 2)) * K + (c1 & 3) * 8;
  const u16* Bg0 = Bw + (size_t)(bn0 + (c0 >> 2)) * K + (c0 & 3) * 8;
  const u16* Bg1 = Bw + (size_t)(bn0 + (c1 >> 2)) * K + (c1 & 3) * 8;

  f32x4 acc[4][4] = {};

  for (int kt = 0; kt < K; kt += 32) {
    gload_lds16(Ag0 + kt, &As[c0 * 8]);
    gload_lds16(Ag1 + kt, &As[c1 * 8]);
    gload_lds16(Bg0 + kt, &Bs[c0 * 8]);
    gload_lds16(Bg1 + kt, &Bs[c1 * 8]);
    __syncthreads();
    half8 af[4], bf[4];
#pragma unroll
    for (int f = 0; f < 4; ++f)
      af[f] = *reinterpret_cast<const half8*>(&As[(wm * 64 + f * 16 + l16) * 32 + lhi * 8]);
#pragma unroll
    for (int f = 0; f < 4; ++f)
      bf[f] = *reinterpret_cast<const half8*>(&Bs[(wn * 64 + f * 16 + l16) * 32 + lhi * 8]);
#pragma unroll
    for (int i = 0; i < 4; ++i)
#pragma unroll
      for (int j = 0; j < 4; ++j)
        acc[i][j] = MFMAH(af[i], bf[j], acc[i][j]);
    __syncthreads();
  }

#pragma unroll
  for (int i = 0; i < 4; ++i) {
    const int m0 = bm0 + wm * 64 + i * 16 + lhi * 4;
#pragma unroll
    for (int j = 0; j < 4; ++j) {
      const int n = bn0 + wn * 64 + j * 16 + l16;
      const float bb = bias[n];
      if (MODE == 0) {
        float* Cf = (float*)Cv;
#pragma unroll
        for (int r = 0; r < 4; ++r)
          Cf[(size_t)(m0 + r) * N + n] = acc[i][j][r] + bb;
      } else if (MODE == 2) {
        u16* C = (u16*)Cv;
        u16x4 pack;
#pragma unroll
        for (int r = 0; r < 4; ++r) pack[r] = f2h(acc[i][j][r] + bb);
        const int head = (m0 >> 11) * 16 + (n >> 6);
        const int s0 = m0 & 2047;
        const int d = n & 63;
        const size_t idx = (((size_t)head * 64 + (s0 >> 5)) * 64 + d) * 32 +
                           ((s0 >> 2) & 3) * 8 + ((s0 >> 4) & 1) * 4;
        *reinterpret_cast<u16x4*>(&C[idx]) = pack;
      } else {
        u16* C = (u16*)Cv;
#pragma unroll
        for (int r = 0; r < 4; ++r) {
          const int m = m0 + r;
          const size_t idx =
              ((size_t)((m >> 11) * 16 + (n >> 6)) * 2048 + (m & 2047)) * 64 + (n & 63);
          C[idx] = f2h((acc[i][j][r] + bb) * scale);
        }
      }
    }
  }
}

// ---------------- Flash attention: LDS-staged K/V, 2-phase pipeline, XCD swizzle --------
// Q,K: [B,H,S,D] fp16 (Q pre-scaled by log2e); VL: fragment-order V; X: [B,S,H*D] fp16
// 1024 blocks, 4 waves each (32 q-rows/wave). K tile staged with XOR-swizzle
// (byte ^ ((row&7)<<4)) applied on the GLOBAL source (linear LDS dest, rule #21);
// V tile (fragment-order) staged linearly, reads conflict-free by construction.
__global__ __launch_bounds__(256, 4) void attn_fwd(const u16* __restrict__ Q,
                                                   const u16* __restrict__ Kh,
                                                   const u16* __restrict__ VL,
                                                   u16* __restrict__ X) {
  __shared__ u16 Ks[2][4096];  // 64 keys x 64 d (swizzled)
  __shared__ u16 Vs[2][4096];  // 2 fragment-order sub-blocks (32 keys each)

  const int tid = threadIdx.x, lane = tid & 63, w = tid >> 6;
  const int l16 = lane & 15, lhi = lane >> 4;
  // XCD-aware decomposition: each XCD gets 8 consecutive heads (K/V L2-resident)
  const int blk = blockIdx.x;
  const int xcd = blk & 7, wi = blk >> 3;
  const int bh = (xcd << 3) | (wi >> 4);
  const int qt = wi & 15;
  const int b = bh >> 4, h = bh & 15;

  const size_t qrow0 = (size_t)bh * 2048 + qt * 128 + w * 32;
  half8 qf[2][2];
#pragma unroll
  for (int fq = 0; fq < 2; ++fq)
#pragma unroll
    for (int ks = 0; ks < 2; ++ks)
      qf[fq][ks] = *reinterpret_cast<const half8*>(
          &Q[(qrow0 + fq * 16 + l16) * 64 + ks * 32 + lhi * 8]);

  f32x4 o[2][4] = {};
  float mrow[2] = {-1e30f, -1e30f};
  float ssum[2] = {0.0f, 0.0f};

  const u16* Kb = Kh + (size_t)bh * 2048 * 64;
  const u16* VLh = VL + (size_t)bh * 64 * 64 * 32;

#define STAGE_KV(bufidx, tt)                                                      \
  do {                                                                            \
    const int kb0_ = (tt) * 64;                                                   \
    _Pragma("unroll")                                                             \
    for (int ii_ = 0; ii_ < 2; ++ii_) {                                           \
      const int c_ = tid + ii_ * 256;                                             \
      const int r_ = c_ >> 3, cb_ = c_ & 7;                                       \
      gload_lds16(Kb + (size_t)(kb0_ + r_) * 64 + ((cb_ ^ (r_ & 7)) << 3),        \
                  &Ks[bufidx][c_ * 8]);                                           \
      gload_lds16(VLh + (size_t)(tt) * 4096 + c_ * 8, &Vs[bufidx][c_ * 8]);       \
    }                                                                             \
  } while (0)

  STAGE_KV(0, 0);
  __syncthreads();

  for (int t = 0; t < 32; ++t) {
    const int cur = t & 1;
    if (t < 31) STAGE_KV(cur ^ 1, t + 1);  // issue next-tile loads BEFORE compute
    // ---- QK^T from swizzled K in LDS (rows=keys, cols=q) ----
    f32x4 sc[2][4] = {};
#pragma unroll
    for (int fk = 0; fk < 4; ++fk) {
      const int row = fk * 16 + l16;
#pragma unroll
      for (int ks = 0; ks < 2; ++ks) {
        const int off = (row * 64 + ks * 32 + lhi * 8) ^ ((row & 7) << 3);
        const half8 kf = *reinterpret_cast<const half8*>(&Ks[cur][off]);
#pragma unroll
        for (int fq = 0; fq < 2; ++fq) sc[fq][fk] = MFMAH(kf, qf[fq][ks], sc[fq][fk]);
      }
    }
    // ---- defer-max online softmax (no cross-lane in common path) ----
    float lm[2];
#pragma unroll
    for (int fq = 0; fq < 2; ++fq) {
      float v = sc[fq][0][0];
#pragma unroll
      for (int fk = 0; fk < 4; ++fk)
#pragma unroll
        for (int r = 0; r < 4; ++r) v = fmaxf(v, sc[fq][fk][r]);
      lm[fq] = v;
    }
    const int trig = (lm[0] > mrow[0] + THR) || (lm[1] > mrow[1] + THR);
    if (__any(trig)) {
#pragma unroll
      for (int fq = 0; fq < 2; ++fq) {
        float rm = lm[fq];
        rm = fmaxf(rm, __shfl_xor(rm, 16));
        rm = fmaxf(rm, __shfl_xor(rm, 32));
        const float nm = fmaxf(mrow[fq], rm);
        const float scl = __builtin_amdgcn_exp2f(mrow[fq] - nm);
        mrow[fq] = nm;
        ssum[fq] *= scl;
        float sb[4];
#pragma unroll
        for (int r = 0; r < 4; ++r) sb[r] = __shfl(scl, lhi * 4 + r);
#pragma unroll
        for (int fd = 0; fd < 4; ++fd)
#pragma unroll
          for (int r = 0; r < 4; ++r) o[fq][fd][r] *= sb[r];
      }
    }
    // ---- exp2 + pack P to fp16 ----
    half8 pa2[2][2];
#pragma unroll
    for (int fq = 0; fq < 2; ++fq) {
      union { half8 v[2]; h2 hh[8]; } uu;
#pragma unroll
      for (int fk = 0; fk < 4; ++fk) {
        const float p0 = __builtin_amdgcn_exp2f(sc[fq][fk][0] - mrow[fq]);
        const float p1 = __builtin_amdgcn_exp2f(sc[fq][fk][1] - mrow[fq]);
        const float p2 = __builtin_amdgcn_exp2f(sc[fq][fk][2] - mrow[fq]);
        const float p3 = __builtin_amdgcn_exp2f(sc[fq][fk][3] - mrow[fq]);
        ssum[fq] += (p0 + p1) + (p2 + p3);
        uu.hh[fk * 2 + 0] = pkrtz(p0, p1);
        uu.hh[fk * 2 + 1] = pkrtz(p2, p3);
      }
      pa2[fq][0] = uu.v[0];
      pa2[fq][1] = uu.v[1];
    }
    // ---- PV from fragment-order V in LDS ----
#pragma unroll
    for (int fd = 0; fd < 4; ++fd)
#pragma unroll
      for (int ts = 0; ts < 2; ++ts) {
        const half8 vf = *reinterpret_cast<const half8*>(
            &Vs[cur][ts * 2048 + (fd * 16 + l16) * 32 + lhi * 8]);
#pragma unroll
        for (int fq = 0; fq < 2; ++fq) o[fq][fd] = MFMAH(pa2[fq][ts], vf, o[fq][fd]);
      }
    __syncthreads();  // drains vmcnt for next tile's stage; releases buffers
  }
#undef STAGE_KV

  // epilogue: reduce ssum across the 4 lanes of each row, normalize, store
#pragma unroll
  for (int fq = 0; fq < 2; ++fq) {
    float ss = ssum[fq];
    ss += __shfl_xor(ss, 16);
    ss += __shfl_xor(ss, 32);
    float iv[4];
#pragma unroll
    for (int r = 0; r < 4; ++r) iv[r] = 1.0f / __shfl(ss, lhi * 4 + r);
#pragma unroll
    for (int r = 0; r < 4; ++r) {
      const int q = qt * 128 + w * 32 + fq * 16 + lhi * 4 + r;
#pragma unroll
      for (int fd = 0; fd < 4; ++fd) {
        const int col = h * 64 + fd * 16 + l16;
        X[((size_t)b * 2048 + q) * 1024 + col] = f2h(o[fq][fd][r] * iv[r]);
      }
    }
  }
}

__global__ void write_loss(float* out, int idx) { out[idx] = 0.0f; }

// ---------------- launch ----------------
extern "C" void kernel_launch(void* const* d_in, const int* in_sizes, int n_in,
                              void* d_out, int out_size, void* d_ws, size_t ws_size,
                              hipStream_t stream) {
  const float* q_f  = (const float*)d_in[0];
  const float* k_f  = (const float*)d_in[1];
  const float* v_f  = (const float*)d_in[2];
  const float* Wq_f = (const float*)d_in[4];
  const float* bq   = (const float*)d_in[5];
  const float* Wk_f = (const float*)d_in[6];
  const float* bk   = (const float*)d_in[7];
  const float* Wv_f = (const float*)d_in[8];
  const float* bv   = (const float*)d_in[9];
  const float* Wo_f = (const float*)d_in[10];
  const float* bo   = (const float*)d_in[11];

  const int SZ = 4 * 2048 * 1024;  // 8388608
  const int SW = 1024 * 1024;      // 1048576

  u16* ws = (u16*)d_ws;
  u16* qb   = ws;                // fp16 inputs
  u16* kbuf = qb + SZ;
  u16* vbuf = kbuf + SZ;
  u16* wqb = vbuf + SZ;          // fp16 weights
  u16* wkb = wqb + SW;
  u16* wvb = wkb + SW;
  u16* wob = wvb + SW;
  u16* Qb  = wob + SW;           // [B,H,S,D], pre-scaled by log2e
  u16* Kb  = Qb + SZ;            // [B,H,S,D]
  u16* VLb = Kb + SZ;            // fragment-order V
  u16* Xb  = VLb + SZ;           // [B,S,H*D]
  const size_t need_bytes = (size_t)(7 * SZ + 4 * SW) * 2;
  if (ws_size < need_bytes) return;

  conv_f32_f16<<<2048, 256, 0, stream>>>(q_f, qb, SZ / 8);
  conv_f32_f16<<<2048, 256, 0, stream>>>(k_f, kbuf, SZ / 8);
  conv_f32_f16<<<2048, 256, 0, stream>>>(v_f, vbuf, SZ / 8);
  conv_f32_f16<<<512, 256, 0, stream>>>(Wq_f, wqb, SW / 8);
  conv_f32_f16<<<512, 256, 0, stream>>>(Wk_f, wkb, SW / 8);
  conv_f32_f16<<<512, 256, 0, stream>>>(Wv_f, wvb, SW / 8);
  conv_f32_f16<<<512, 256, 0, stream>>>(Wo_f, wob, SW / 8);

  dim3 gg(1024 / 128, 8192 / 128);
  gemm_bt<1><<<gg, 256, 0, stream>>>(qb, wqb, bq, Qb, 8192, 1024, 1024, LOG2E);
  gemm_bt<1><<<gg, 256, 0, stream>>>(kbuf, wkb, bk, Kb, 8192, 1024, 1024, 1.0f);
  gemm_bt<2><<<gg, 256, 0, stream>>>(vbuf, wvb, bv, VLb, 8192, 1024, 1024, 1.0f);

  attn_fwd<<<dim3(1024), 256, 0, stream>>>(Qb, Kb, VLb, Xb);

  gemm_bt<0><<<gg, 256, 0, stream>>>(Xb, wob, bo, d_out, 8192, 1024, 1024, 1.0f);
  write_loss<<<1, 1, 0, stream>>>((float*)d_out, out_size - 1);
}